// Round 3
// baseline (574.646 us; speedup 1.0000x reference)
//
#include <hip/hip_runtime.h>

// KnowledgeEmbedding loss as 8 fused fp32 GEMMs (M=4096, N=256, K=100) with
// softplus-sum epilogue and fused positive term.
// score(row,neg) = dot(head[h_row]+rvec, tail[neg]) + bias[t_row]
// loss = (1/B) * sum_rel [ sum_row softplus(-pos_row) + sum_{row,neg} softplus(score) ]
//
// Tiling: block = 64 rows x 128 negs, K chunked 5x20, double-buffered LDS
// (1 barrier per chunk). Thread tile 8x4 (tx=tid&7 rows, ty=tid>>3 negs):
// As frag read 2x b128 @ tx*32B (2-way, free); Bs frag read 1x b128 @ ty*16B
// (conflict-free). Grid = 8 rel * 64 rowblk * 2 negblk = 1024 blocks.

#define EMBED   100
#define BATCH   4096
#define NUM_NEG 256
#define KC      20
#define BM      64
#define BN      128
#define NCHUNK  5

struct RelP {
    const float* head;
    const float* tail;
    const float* bias;
    int hc, tc;
};

struct Params {
    RelP rel[8];
    const float* rel_vecs;
    const int*   batch_idxs;
    const int*   neg_idxs;
    float*       out;
};

__device__ __forceinline__ float softplus_f(float x) {
    // softplus(x) = max(x,0) + log1p(exp(-|x|))
    float e = __expf(-fabsf(x));
    return fmaxf(x, 0.0f) + __logf(1.0f + e);
}

__launch_bounds__(256, 4)
__global__ void ke_kernel(Params p) {
    const int bid = blockIdx.x;
    const int r   = bid & 7;
    const int rb  = (bid >> 3) & 63;
    const int nb  = bid >> 9;            // 0..1
    const int tid = threadIdx.x;
    const int tx  = tid & 7;             // row group: rows tx*8 .. +7
    const int ty  = tid >> 3;            // neg group: negs ty*4 .. +3

    __shared__ float As[2][KC * BM];     // [k][row], ex = head+rvec fused
    __shared__ float Bs[2][KC * BN];     // [k][neg]

    const RelP rp = p.rel[r];

    // ---- staging assignments (fixed across chunks) ----
    // A: 64 rows x 5 float4/chunk = 320 items. f=tid: row=f&63, j=f>>6(0..3);
    //    f=256+tid (tid<64): row=tid, j=4.
    const int arow0 = tid & 63;
    const int aj0   = tid >> 6;
    const int h0    = p.batch_idxs[(rb * BM + arow0) * 8 + rp.hc];
    const float* aptr0 = rp.head + (size_t)h0 * EMBED + aj0 * 4;
    const float* rvp0  = p.rel_vecs + r * EMBED + aj0 * 4;
    const bool  doA1 = (tid < 64);
    const int   h1   = doA1 ? p.batch_idxs[(rb * BM + tid) * 8 + rp.hc] : 0;
    const float* aptr1 = rp.head + (size_t)h1 * EMBED + 16;
    const float* rvp1  = p.rel_vecs + r * EMBED + 16;

    // B: 128 negs x 5 float4/chunk = 640 items. f=tid: neg=f&127, j=f>>7(0..1);
    //    f=256+tid: j+2; f=512+tid (tid<128): neg=tid, j=4.
    const int bneg0 = tid & 127;
    const int bj0   = tid >> 7;          // 0..1
    const int n0    = p.neg_idxs[r * NUM_NEG + nb * BN + bneg0];
    const float* bptr0 = rp.tail + (size_t)n0 * EMBED + bj0 * 4;
    const float* bptr1 = bptr0 + 8;      // (bj0+2)*4
    const bool  doB2 = (tid < 128);
    const int   n2   = doB2 ? p.neg_idxs[r * NUM_NEG + nb * BN + tid] : 0;
    const float* bptr2 = rp.tail + (size_t)n2 * EMBED + 16;

    float acc[8][4];
#pragma unroll
    for (int i = 0; i < 8; ++i)
#pragma unroll
        for (int n = 0; n < 4; ++n) acc[i][n] = 0.0f;

    // prefetch registers
    float4 pa0, prv0, pa1, prv1, pb0, pb1, pb2;

    auto load_chunk = [&](int kc) {
        const int k0 = kc * KC;
        pa0  = *(const float4*)(aptr0 + k0);
        prv0 = *(const float4*)(rvp0 + k0);
        if (doA1) { pa1 = *(const float4*)(aptr1 + k0); prv1 = *(const float4*)(rvp1 + k0); }
        pb0 = *(const float4*)(bptr0 + k0);
        pb1 = *(const float4*)(bptr1 + k0);
        if (doB2) pb2 = *(const float4*)(bptr2 + k0);
    };

    auto write_buf = [&](int b) {
        {
            const int kb = aj0 * 4;
            As[b][(kb + 0) * BM + arow0] = pa0.x + prv0.x;
            As[b][(kb + 1) * BM + arow0] = pa0.y + prv0.y;
            As[b][(kb + 2) * BM + arow0] = pa0.z + prv0.z;
            As[b][(kb + 3) * BM + arow0] = pa0.w + prv0.w;
        }
        if (doA1) {
            As[b][16 * BM + tid] = pa1.x + prv1.x;
            As[b][17 * BM + tid] = pa1.y + prv1.y;
            As[b][18 * BM + tid] = pa1.z + prv1.z;
            As[b][19 * BM + tid] = pa1.w + prv1.w;
        }
        {
            const int kb = bj0 * 4;
            Bs[b][(kb + 0) * BN + bneg0] = pb0.x;
            Bs[b][(kb + 1) * BN + bneg0] = pb0.y;
            Bs[b][(kb + 2) * BN + bneg0] = pb0.z;
            Bs[b][(kb + 3) * BN + bneg0] = pb0.w;
        }
        {
            const int kb = bj0 * 4 + 8;
            Bs[b][(kb + 0) * BN + bneg0] = pb1.x;
            Bs[b][(kb + 1) * BN + bneg0] = pb1.y;
            Bs[b][(kb + 2) * BN + bneg0] = pb1.z;
            Bs[b][(kb + 3) * BN + bneg0] = pb1.w;
        }
        if (doB2) {
            Bs[b][16 * BN + tid] = pb2.x;
            Bs[b][17 * BN + tid] = pb2.y;
            Bs[b][18 * BN + tid] = pb2.z;
            Bs[b][19 * BN + tid] = pb2.w;
        }
    };

    auto compute = [&](int b) {
#pragma unroll
        for (int k = 0; k < KC; ++k) {
            const float4 a0 = *(const float4*)&As[b][k * BM + tx * 8];
            const float4 a1 = *(const float4*)&As[b][k * BM + tx * 8 + 4];
            const float4 bv = *(const float4*)&Bs[b][k * BN + ty * 4];
            const float av[8] = {a0.x, a0.y, a0.z, a0.w, a1.x, a1.y, a1.z, a1.w};
            const float bw[4] = {bv.x, bv.y, bv.z, bv.w};
#pragma unroll
            for (int i = 0; i < 8; ++i)
#pragma unroll
                for (int n = 0; n < 4; ++n)
                    acc[i][n] = fmaf(av[i], bw[n], acc[i][n]);
        }
    };

    // ---- pipelined main loop: 1 barrier per chunk ----
    load_chunk(0);
    write_buf(0);
    __syncthreads();
#pragma unroll
    for (int kc = 0; kc < NCHUNK; ++kc) {
        if (kc + 1 < NCHUNK) load_chunk(kc + 1);   // issue globals early
        compute(kc & 1);
        if (kc + 1 < NCHUNK) {
            write_buf((kc + 1) & 1);               // other buffer: no WAR hazard
            __syncthreads();
        }
    }

    // ---- epilogue: bias + softplus + sum ----
    float local = 0.0f;
#pragma unroll
    for (int i = 0; i < 8; ++i) {
        const int grow = rb * BM + tx * 8 + i;
        const int t    = p.batch_idxs[grow * 8 + rp.tc];
        const float bias = rp.bias[t];
#pragma unroll
        for (int n = 0; n < 4; ++n)
            local += softplus_f(acc[i][n] + bias);
    }

    // ---- fused positive term: nb==0 blocks, one row per thread 0..63 ----
    if (nb == 0 && tid < BM) {
        const int row = rb * BM + tid;
        const int h = p.batch_idxs[row * 8 + rp.hc];
        const int t = p.batch_idxs[row * 8 + rp.tc];
        const float4* __restrict__ hv  = (const float4*)(rp.head + (size_t)h * EMBED);
        const float4* __restrict__ rv4 = (const float4*)(p.rel_vecs + r * EMBED);
        const float4* __restrict__ tv  = (const float4*)(rp.tail + (size_t)t * EMBED);
        float d0 = 0.f, d1 = 0.f, d2 = 0.f, d3 = 0.f;
#pragma unroll
        for (int j = 0; j < EMBED / 4; ++j) {
            const float4 a = hv[j];
            const float4 b = rv4[j];
            const float4 v = tv[j];
            d0 = fmaf(a.x + b.x, v.x, d0);
            d1 = fmaf(a.y + b.y, v.y, d1);
            d2 = fmaf(a.z + b.z, v.z, d2);
            d3 = fmaf(a.w + b.w, v.w, d3);
        }
        const float pos = ((d0 + d1) + (d2 + d3)) + rp.bias[t];
        local += softplus_f(-pos);
    }

    // ---- block reduction + one atomic ----
#pragma unroll
    for (int off = 32; off > 0; off >>= 1)
        local += __shfl_down(local, off, 64);
    __shared__ float wsum[4];
    const int wid  = tid >> 6;
    const int lane = tid & 63;
    if (lane == 0) wsum[wid] = local;
    __syncthreads();
    if (tid == 0) {
        const float s = (wsum[0] + wsum[1]) + (wsum[2] + wsum[3]);
        atomicAdd(p.out, s * (1.0f / BATCH));
    }
}

extern "C" void kernel_launch(void* const* d_in, const int* in_sizes, int n_in,
                              void* d_out, int out_size, void* d_ws, size_t ws_size,
                              hipStream_t stream) {
    const float* user  = (const float*)d_in[0];
    const float* prod  = (const float*)d_in[1];
    const float* word  = (const float*)d_in[2];
    const float* brand = (const float*)d_in[3];
    const float* cat   = (const float*)d_in[4];
    const float* rprod = (const float*)d_in[5];

    Params p;
    p.rel_vecs   = (const float*)d_in[6];
    p.batch_idxs = (const int*)d_in[15];
    p.neg_idxs   = (const int*)d_in[16];
    p.out        = (float*)d_out;

    p.rel[0] = {user, prod,  (const float*)d_in[7],  0, 1};  // purchase
    p.rel[1] = {user, word,  (const float*)d_in[8],  0, 2};  // mentions
    p.rel[2] = {prod, word,  (const float*)d_in[9],  1, 2};  // describe
    p.rel[3] = {prod, brand, (const float*)d_in[10], 1, 3};  // produced
    p.rel[4] = {prod, cat,   (const float*)d_in[11], 1, 4};  // belongs
    p.rel[5] = {prod, rprod, (const float*)d_in[12], 1, 5};  // also_bought
    p.rel[6] = {prod, rprod, (const float*)d_in[13], 1, 6};  // also_viewed
    p.rel[7] = {prod, rprod, (const float*)d_in[14], 1, 7};  // together

    hipMemsetAsync(d_out, 0, sizeof(float), stream);
    ke_kernel<<<1024, 256, 0, stream>>>(p);
}